// Round 16
// baseline (598.258 us; speedup 1.0000x reference)
//
#include <hip/hip_runtime.h>
#include <hip/hip_bf16.h>

typedef float  f32x4 __attribute__((ext_vector_type(4)));
typedef short  s16x8 __attribute__((ext_vector_type(8)));

#define NB   1024
#define SEQ  64
#define DIM  512
#define NH   8
#define SCALE 0.044194173824159216f

// round-half-up f32->bf16: 2 VALU ops
static __device__ __forceinline__ unsigned short f2bf(float f) {
    unsigned u = __builtin_bit_cast(unsigned, f);
    return (unsigned short)((u + 0x8000u) >> 16);
}

static __device__ __forceinline__ f32x4 mma(s16x8 a, s16x8 b, f32x4 c) {
    return __builtin_amdgcn_mfma_f32_16x16x32_bf16(a, b, c, 0, 0, 0);
}

static __device__ __forceinline__ s16x8 cvt2(float4 a, float4 b) {
    s16x8 x;
    x[0] = (short)f2bf(a.x); x[1] = (short)f2bf(a.y);
    x[2] = (short)f2bf(a.z); x[3] = (short)f2bf(a.w);
    x[4] = (short)f2bf(b.x); x[5] = (short)f2bf(b.y);
    x[6] = (short)f2bf(b.z); x[7] = (short)f2bf(b.w);
    return x;
}

// Pre-kernel: Wq, Wc (f32 [512][512] row-major [k][n]) -> bf16 B-fragment order.
__global__ __launch_bounds__(256) void prep_weights(
    const float* __restrict__ Wq, const float* __restrict__ Wc,
    unsigned short* __restrict__ wf)
{
    int gid  = blockIdx.x * 256 + threadIdx.x;   // 0..65535
    int m    = gid >> 15;
    int tile = (gid >> 10) & 31;
    int ks   = (gid >> 6) & 15;
    int lane = gid & 63;
    const float* W = m ? Wc : Wq;
    int col = tile * 16 + (lane & 15);
    int k0  = ks * 32 + (lane >> 4) * 8;
    unsigned short* dst = wf + (size_t)gid * 8;
#pragma unroll
    for (int j = 0; j < 8; ++j)
        dst[j] = f2bf(W[(size_t)(k0 + j) * DIM + col]);
}

// Pre-kernel: f32 acts -> bf16 in the EXACT swizzled LDS image order
// (R12/R13-verified layout), so the fused kernel stages with linear
// global_load_lds (rule #21: linear dest + pre-permuted source).
// Image granule d (16B) of tile tb = m*NB+b holds bf16 of
// act[row][p*64+kk*32+q*8 .. +7] with p=d>>9, kk=(d>>8)&1, q=(d>>6)&3,
// row=(d&63)^(4*kk+q)  (XOR touches only row bits: involution).
__global__ __launch_bounds__(256) void prep_acts_swz(
    const float* __restrict__ qin, const float* __restrict__ cin,
    unsigned short* __restrict__ acts)
{
    size_t g0 = ((size_t)blockIdx.x * 256 + threadIdx.x) * 2;
#pragma unroll
    for (int t = 0; t < 2; ++t) {
        size_t g  = g0 + t;
        int    d  = (int)(g & 4095);
        size_t tb = g >> 12;                       // m*NB + b
        const float* act = (tb >= NB)
            ? cin + (tb - NB) * (size_t)SEQ * DIM
            : qin + tb * (size_t)SEQ * DIM;
        int p  = d >> 9, kk = (d >> 8) & 1, qq = (d >> 6) & 3;
        int row = (d & 63) ^ (4 * kk + qq);
        const float* src = act + (size_t)row * DIM + p * 64 + kk * 32 + qq * 8;
        float4 a  = *(const float4*)src;
        float4 b2 = *(const float4*)(src + 4);
        *(s16x8*)(acts + g * 8) = cvt2(a, b2);
    }
}

// async global->LDS, 16B/lane: LDS dest = uniform base + lane*16 (implicit),
// global src = per-lane. Both sides linear thanks to prep_acts_swz.
#define GLL16(GP, LP)                                                          \
    __builtin_amdgcn_global_load_lds(                                          \
        (const unsigned int __attribute__((address_space(1)))*)(const void*)(GP), \
        (unsigned int __attribute__((address_space(3)))*)(void*)(LP), 16, 0, 0)

// ====================== Persistent fused kernel (gll staging) ==============
// Grid 256 x 512 thr (one block/CU), 4 batches each (b = blk + 256*n).
// Staging = 16 global_load_lds issues (8/wave/region), ZERO registers held
// (R15's reg-held prefetch spilled: WRITE 676MB). Pipelining:
//   next-Q issued after GEMM-Q's barrier (flies under Qp->T + tail),
//   next-C issued at loop head (T region frees at tail-end barrier).
// GEMM16 + tail are R13-verbatim (layout algebra unchanged).
// NOTE: plain __launch_bounds__ — min-waves 2nd arg clamps unified VGPR/AGPR
// below the 64-AGPR acc -> spills (rounds 2, 7).
__global__ __launch_bounds__(512) void fused_gll(
    const unsigned short* __restrict__ acts,   // [2*NB][4096] 16B granules
    const float* __restrict__ bq,
    const float* __restrict__ bc,
    const unsigned short* __restrict__ wf,
    float* __restrict__ out)
{
    __shared__ unsigned short smem[69632];     // Q 32768 + region2 36864 shorts
    unsigned short* Q = smem;
    unsigned short* C = smem + 32768;

    const int tid  = threadIdx.x;
    const int lane = tid & 63;
    const int wv   = tid >> 6;
    const int l15  = lane & 15;
    const int l4   = lane >> 4;
    const int blk  = blockIdx.x;

    unsigned short (*T)[72] = (unsigned short(*)[72])(C + wv * 4608);
    const f32x4 fz = {0.f, 0.f, 0.f, 0.f};

#define STAGE_TILE(SRC, REGION)                                                \
    {                                                                          \
        _Pragma("unroll")                                                      \
        for (int i_ = 0; i_ < 8; ++i_) {                                       \
            const int so_ = wv * 4096 + i_ * 512;                              \
            GLL16((SRC) + so_ + lane * 8, &(REGION)[so_]);                     \
        }                                                                      \
    }

#define GEMM16(REGION, WFM)                                                    \
    {                                                                          \
        _Pragma("unroll")                                                      \
        for (int ks = 0; ks < 16; ++ks) {                                      \
            const int p_ = ks >> 1, kk_ = ks & 1;                              \
            s16x8 af[4], bf[4];                                                \
            _Pragma("unroll")                                                  \
            for (int mt = 0; mt < 4; ++mt) {                                   \
                const int s_ = p_ * 512 + kk_ * 256 + l4 * 64 + mt * 16 + l15; \
                af[mt] = *(const s16x8*)&(REGION)[(s_ ^ (4 * kk_ + l4)) * 8];  \
            }                                                                  \
            _Pragma("unroll")                                                  \
            for (int nt = 0; nt < 4; ++nt)                                     \
                bf[nt] = *(const s16x8*)((WFM) +                               \
                         ((size_t)((wv * 4 + nt) * 16 + ks) * 64 + lane) * 8); \
            _Pragma("unroll")                                                  \
            for (int mt = 0; mt < 4; ++mt)                                     \
                _Pragma("unroll")                                              \
                for (int nt = 0; nt < 4; ++nt)                                 \
                    acc[mt][nt] = mma(af[mt], bf[nt], acc[mt][nt]);            \
        }                                                                      \
    }

    // prologue: stage Q_0 and C_0 (the only fully exposed stage per block)
    STAGE_TILE(acts + (size_t)blk * 32768, Q);
    STAGE_TILE(acts + (size_t)(NB + blk) * 32768, C);
    __syncthreads();

    for (int n = 0; n < 4; ++n) {
        const int b = blk + 256 * n;

        f32x4 acc[4][4];
#pragma unroll
        for (int x = 0; x < 4; ++x)
#pragma unroll
            for (int y = 0; y < 4; ++y) acc[x][y] = fz;

        // ---------------- GEMM-C ----------------
        GEMM16(C, wf + 262144);
        __syncthreads();   // all waves done reading C before T overwrites it

        // Cp + bias -> per-wave tail tile; cb frags (Cp^T = contig rows)
#pragma unroll
        for (int nt = 0; nt < 4; ++nt) {
            float bcv = bc[wv * 64 + nt * 16 + l15];
#pragma unroll
            for (int mt = 0; mt < 4; ++mt)
#pragma unroll
                for (int r = 0; r < 4; ++r)
                    T[mt * 16 + l4 * 4 + r][nt * 16 + l15] = f2bf(acc[mt][nt][r] + bcv);
        }
        s16x8 cb[4][2];
#pragma unroll
        for (int nt = 0; nt < 4; ++nt)
#pragma unroll
            for (int ks = 0; ks < 2; ++ks)
                cb[nt][ks] = *(const s16x8*)&T[nt * 16 + l15][ks * 32 + l4 * 8];

        // ---------------- GEMM-Q (same acc regs) ----------------
#pragma unroll
        for (int x = 0; x < 4; ++x)
#pragma unroll
            for (int y = 0; y < 4; ++y) acc[x][y] = fz;
        GEMM16(Q, wf);
        __syncthreads();   // Q region dead for this batch

        // next-Q prefetch: reg-free, flies under Qp->T + tail
        if (n < 3) STAGE_TILE(acts + (size_t)(b + 256) * 32768, Q);

        // Qp + bias -> T (overwrites Cp; cb in regs); qa/qb frags
#pragma unroll
        for (int nt = 0; nt < 4; ++nt) {
            float bqv = bq[wv * 64 + nt * 16 + l15];
#pragma unroll
            for (int mt = 0; mt < 4; ++mt)
#pragma unroll
                for (int r = 0; r < 4; ++r)
                    T[mt * 16 + l4 * 4 + r][nt * 16 + l15] = f2bf(acc[mt][nt][r] + bqv);
        }
        s16x8 qa[4][2], qb[4][2];
#pragma unroll
        for (int mt = 0; mt < 4; ++mt)
#pragma unroll
            for (int ks = 0; ks < 2; ++ks)
                qa[mt][ks] = *(const s16x8*)&T[mt * 16 + l15][ks * 32 + l4 * 8];
#pragma unroll
        for (int nt = 0; nt < 4; ++nt)
#pragma unroll
            for (int ks = 0; ks < 2; ++ks) {
                s16x8 v;
#pragma unroll
                for (int j = 0; j < 8; ++j)
                    v[j] = (short)T[ks * 32 + l4 * 8 + j][nt * 16 + l15];
                qb[nt][ks] = v;
            }

        // ---------------- attention tail (R13-proven) ----------------
        f32x4 Sc[4][4];
#pragma unroll
        for (int x = 0; x < 4; ++x)
#pragma unroll
            for (int y = 0; y < 4; ++y) Sc[x][y] = fz;
#pragma unroll
        for (int ks = 0; ks < 2; ++ks)
#pragma unroll
            for (int mt = 0; mt < 4; ++mt)
#pragma unroll
                for (int nt = 0; nt < 4; ++nt)
                    Sc[mt][nt] = mma(qa[mt][ks], cb[nt][ks], Sc[mt][nt]);

        // softmax over keys (rows): P1 -> T
#pragma unroll
        for (int mt = 0; mt < 4; ++mt)
#pragma unroll
            for (int r = 0; r < 4; ++r) {
                float m = fmaxf(fmaxf(Sc[mt][0][r], Sc[mt][1][r]),
                                fmaxf(Sc[mt][2][r], Sc[mt][3][r]));
                m = fmaxf(m, __shfl_xor(m, 1));
                m = fmaxf(m, __shfl_xor(m, 2));
                m = fmaxf(m, __shfl_xor(m, 4));
                m = fmaxf(m, __shfl_xor(m, 8));
                float e[4], s = 0.f;
#pragma unroll
                for (int nt = 0; nt < 4; ++nt) { e[nt] = __expf(SCALE * (Sc[mt][nt][r] - m)); s += e[nt]; }
                s += __shfl_xor(s, 1);
                s += __shfl_xor(s, 2);
                s += __shfl_xor(s, 4);
                s += __shfl_xor(s, 8);
                float inv = 1.f / s;
                int r3 = mt * 16 + l4 * 4 + r;
#pragma unroll
                for (int nt = 0; nt < 4; ++nt)
                    T[r3][nt * 16 + l15] = f2bf(e[nt] * inv);
            }

        s16x8 pa[4][2];
#pragma unroll
        for (int mt = 0; mt < 4; ++mt)
#pragma unroll
            for (int ks = 0; ks < 2; ++ks)
                pa[mt][ks] = *(const s16x8*)&T[mt * 16 + l15][ks * 32 + l4 * 8];

        // softmax over queries (cols): P2^T -> T
#pragma unroll
        for (int nt = 0; nt < 4; ++nt) {
            float m = -1e30f;
#pragma unroll
            for (int mt = 0; mt < 4; ++mt)
#pragma unroll
                for (int r = 0; r < 4; ++r) m = fmaxf(m, Sc[mt][nt][r]);
            m = fmaxf(m, __shfl_xor(m, 16));
            m = fmaxf(m, __shfl_xor(m, 32));
            float ee[4][4], s = 0.f;
#pragma unroll
            for (int mt = 0; mt < 4; ++mt)
#pragma unroll
                for (int r = 0; r < 4; ++r) { ee[mt][r] = __expf(SCALE * (Sc[mt][nt][r] - m)); s += ee[mt][r]; }
            s += __shfl_xor(s, 16);
            s += __shfl_xor(s, 32);
            float inv = 1.f / s;
            int krow = nt * 16 + l15;
#pragma unroll
            for (int mt = 0; mt < 4; ++mt)
#pragma unroll
                for (int r = 0; r < 4; ++r)
                    T[krow][mt * 16 + l4 * 4 + r] = f2bf(ee[mt][r] * inv);
        }

        // c_coattn = P1 @ Cp^T ; store
        f32x4 O[4][4];
#pragma unroll
        for (int x = 0; x < 4; ++x)
#pragma unroll
            for (int y = 0; y < 4; ++y) O[x][y] = fz;
#pragma unroll
        for (int ks = 0; ks < 2; ++ks)
#pragma unroll
            for (int mt = 0; mt < 4; ++mt)
#pragma unroll
                for (int nt = 0; nt < 4; ++nt)
                    O[mt][nt] = mma(pa[mt][ks], cb[nt][ks], O[mt][nt]);

        float* cO = out;
#pragma unroll
        for (int mt = 0; mt < 4; ++mt)
#pragma unroll
            for (int nt = 0; nt < 4; ++nt)
#pragma unroll
                for (int r = 0; r < 4; ++r) {
                    int qrow = mt * 16 + l4 * 4 + r;
                    cO[((size_t)b * SEQ + qrow) * (NH * 64) + wv * 64 + nt * 16 + l15] = O[mt][nt][r];
                }

        // q_coattn = P2^T @ Qp ; store
        s16x8 p2a[4][2];
#pragma unroll
        for (int mt = 0; mt < 4; ++mt)
#pragma unroll
            for (int ks = 0; ks < 2; ++ks)
                p2a[mt][ks] = *(const s16x8*)&T[mt * 16 + l15][ks * 32 + l4 * 8];

#pragma unroll
        for (int x = 0; x < 4; ++x)
#pragma unroll
            for (int y = 0; y < 4; ++y) O[x][y] = fz;
#pragma unroll
        for (int ks = 0; ks < 2; ++ks)
#pragma unroll
            for (int mt = 0; mt < 4; ++mt)
#pragma unroll
                for (int nt = 0; nt < 4; ++nt)
                    O[mt][nt] = mma(p2a[mt][ks], qb[nt][ks], O[mt][nt]);

        float* qO = out + (size_t)NB * SEQ * NH * 64;
#pragma unroll
        for (int mt = 0; mt < 4; ++mt)
#pragma unroll
            for (int nt = 0; nt < 4; ++nt)
#pragma unroll
                for (int r = 0; r < 4; ++r) {
                    int krow = mt * 16 + l4 * 4 + r;
                    qO[((size_t)b * SEQ + krow) * (NH * 64) + wv * 64 + nt * 16 + l15] = O[mt][nt][r];
                }

        __syncthreads();   // T dead; next-Q glls drained

        // next-C prefetch into the freed T/C region; bar waits its arrival
        if (n < 3) {
            STAGE_TILE(acts + (size_t)(NB + b + 256) * 32768, C);
            __syncthreads();
        }
    }

#undef STAGE_TILE
#undef GEMM16
}

// ====================== Fallback: R13 fused_b (needs only 1 MB ws) =========
__global__ __launch_bounds__(512) void fused_b(
    const float* __restrict__ query,
    const float* __restrict__ context,
    const float* __restrict__ bq,
    const float* __restrict__ bc,
    const unsigned short* __restrict__ wf,
    float* __restrict__ out)
{
    __shared__ unsigned short smem[69632];
    unsigned short* Q = smem;
    unsigned short* C = smem + 32768;

    const int tid  = threadIdx.x;
    const int lane = tid & 63;
    const int wv   = tid >> 6;
    const int l15  = lane & 15;
    const int l4   = lane >> 4;
    const int b    = blockIdx.x;

    const float* gq = query   + (size_t)b * SEQ * DIM;
    const float* gc = context + (size_t)b * SEQ * DIM;

    {
        const int row = tid >> 3;
        const int cw  = tid & 7;
        const int wsb = (cw >> 2) * 256 + (cw & 3) * 64 + row;
        const float* sq = gq + (size_t)row * DIM + cw * 8;
        const float* sc = gc + (size_t)row * DIM + cw * 8;
        float4 lq[16], lc[16];
#pragma unroll
        for (int p = 0; p < 8; ++p) {
            lq[2 * p]     = *(const float4*)(sq + p * 64);
            lq[2 * p + 1] = *(const float4*)(sq + p * 64 + 4);
        }
#pragma unroll
        for (int p = 0; p < 8; ++p) {
            lc[2 * p]     = *(const float4*)(sc + p * 64);
            lc[2 * p + 1] = *(const float4*)(sc + p * 64 + 4);
        }
#pragma unroll
        for (int p = 0; p < 8; ++p) {
            *(s16x8*)&Q[((p * 512 + wsb) ^ cw) * 8] = cvt2(lq[2 * p], lq[2 * p + 1]);
            *(s16x8*)&C[((p * 512 + wsb) ^ cw) * 8] = cvt2(lc[2 * p], lc[2 * p + 1]);
        }
    }
    __syncthreads();

    const f32x4 fz = {0.f, 0.f, 0.f, 0.f};
    f32x4 acc[4][4];
#pragma unroll
    for (int x = 0; x < 4; ++x)
#pragma unroll
        for (int y = 0; y < 4; ++y) acc[x][y] = fz;

    {
        const unsigned short* wfm = wf + 262144;
#pragma unroll
        for (int ks = 0; ks < 16; ++ks) {
            const int p  = ks >> 1;
            const int kk = ks & 1;
            s16x8 af[4], bf[4];
#pragma unroll
            for (int mt = 0; mt < 4; ++mt) {
                const int s = p * 512 + kk * 256 + l4 * 64 + mt * 16 + l15;
                af[mt] = *(const s16x8*)&C[(s ^ (4 * kk + l4)) * 8];
            }
#pragma unroll
            for (int nt = 0; nt < 4; ++nt)
                bf[nt] = *(const s16x8*)(wfm +
                         ((size_t)((wv * 4 + nt) * 16 + ks) * 64 + lane) * 8);
#pragma unroll
            for (int mt = 0; mt < 4; ++mt)
#pragma unroll
                for (int nt = 0; nt < 4; ++nt)
                    acc[mt][nt] = mma(af[mt], bf[nt], acc[mt][nt]);
        }
    }
    __syncthreads();

    unsigned short (*T)[72] = (unsigned short(*)[72])(C + wv * 4608);

#pragma unroll
    for (int nt = 0; nt < 4; ++nt) {
        float bcv = bc[wv * 64 + nt * 16 + l15];
#pragma unroll
        for (int mt = 0; mt < 4; ++mt)
#pragma unroll
            for (int r = 0; r < 4; ++r)
                T[mt * 16 + l4 * 4 + r][nt * 16 + l15] = f2bf(acc[mt][nt][r] + bcv);
    }
    s16x8 cb[4][2];
#pragma unroll
    for (int nt = 0; nt < 4; ++nt)
#pragma unroll
        for (int ks = 0; ks < 2; ++ks)
            cb[nt][ks] = *(const s16x8*)&T[nt * 16 + l15][ks * 32 + l4 * 8];

#pragma unroll
    for (int x = 0; x < 4; ++x)
#pragma unroll
        for (int y = 0; y < 4; ++y) acc[x][y] = fz;

    {
#pragma unroll
        for (int ks = 0; ks < 16; ++ks) {
            const int p  = ks >> 1;
            const int kk = ks & 1;
            s16x8 af[4], bf[4];
#pragma unroll
            for (int mt = 0; mt < 4; ++mt) {
                const int s = p * 512 + kk * 256 + l4 * 64 + mt * 16 + l15;
                af[mt] = *(const s16x8*)&Q[(s ^ (4 * kk + l4)) * 8];
            }
#pragma unroll
            for (int nt = 0; nt < 4; ++nt)
                bf[nt] = *(const s16x8*)(wf +
                         ((size_t)((wv * 4 + nt) * 16 + ks) * 64 + lane) * 8);
#pragma unroll
            for (int mt = 0; mt < 4; ++mt)
#pragma unroll
                for (int nt = 0; nt < 4; ++nt)
                    acc[mt][nt] = mma(af[mt], bf[nt], acc[mt][nt]);
        }
    }

#pragma unroll
    for (int nt = 0; nt < 4; ++nt) {
        float bqv = bq[wv * 64 + nt * 16 + l15];
#pragma unroll
        for (int mt = 0; mt < 4; ++mt)
#pragma unroll
            for (int r = 0; r < 4; ++r)
                T[mt * 16 + l4 * 4 + r][nt * 16 + l15] = f2bf(acc[mt][nt][r] + bqv);
    }
    s16x8 qa[4][2], qb[4][2];
#pragma unroll
    for (int mt = 0; mt < 4; ++mt)
#pragma unroll
        for (int ks = 0; ks < 2; ++ks)
            qa[mt][ks] = *(const s16x8*)&T[mt * 16 + l15][ks * 32 + l4 * 8];
#pragma unroll
    for (int nt = 0; nt < 4; ++nt)
#pragma unroll
        for (int ks = 0; ks < 2; ++ks) {
            s16x8 v;
#pragma unroll
            for (int j = 0; j < 8; ++j)
                v[j] = (short)T[ks * 32 + l4 * 8 + j][nt * 16 + l15];
            qb[nt][ks] = v;
        }

    f32x4 Sc[4][4];
#pragma unroll
    for (int x = 0; x < 4; ++x)
#pragma unroll
        for (int y = 0; y < 4; ++y) Sc[x][y] = fz;
#pragma unroll
    for (int ks = 0; ks < 2; ++ks)
#pragma unroll
        for (int mt = 0; mt < 4; ++mt)
#pragma unroll
            for (int nt = 0; nt < 4; ++nt)
                Sc[mt][nt] = mma(qa[mt][ks], cb[nt][ks], Sc[mt][nt]);

#pragma unroll
    for (int mt = 0; mt < 4; ++mt)
#pragma unroll
        for (int r = 0; r < 4; ++r) {
            float m = fmaxf(fmaxf(Sc[mt][0][r], Sc[mt][1][r]),
                            fmaxf(Sc[mt][2][r], Sc[mt][3][r]));
            m = fmaxf(m, __shfl_xor(m, 1));
            m = fmaxf(m, __shfl_xor(m, 2));
            m = fmaxf(m, __shfl_xor(m, 4));
            m = fmaxf(m, __shfl_xor(m, 8));
            float e[4], s = 0.f;
#pragma unroll
            for (int nt = 0; nt < 4; ++nt) { e[nt] = __expf(SCALE * (Sc[mt][nt][r] - m)); s += e[nt]; }
            s += __shfl_xor(s, 1);
            s += __shfl_xor(s, 2);
            s += __shfl_xor(s, 4);
            s += __shfl_xor(s, 8);
            float inv = 1.f / s;
            int row = mt * 16 + l4 * 4 + r;
#pragma unroll
            for (int nt = 0; nt < 4; ++nt)
                T[row][nt * 16 + l15] = f2bf(e[nt] * inv);
        }

    s16x8 pa[4][2];
#pragma unroll
    for (int mt = 0; mt < 4; ++mt)
#pragma unroll
        for (int ks = 0; ks < 2; ++ks)
            pa[mt][ks] = *(const s16x8*)&T[mt * 16 + l15][ks * 32 + l4 * 8];

#pragma unroll
    for (int nt = 0; nt < 4; ++nt) {
        float m = -1e30f;
#pragma unroll
        for (int mt = 0; mt < 4; ++mt)
#pragma unroll
            for (int r = 0; r < 4; ++r) m = fmaxf(m, Sc[mt][nt][r]);
        m = fmaxf(m, __shfl_xor(m, 16));
        m = fmaxf(m, __shfl_xor(m, 32));
        float ee[4][4], s = 0.f;
#pragma unroll
        for (int mt = 0; mt < 4; ++mt)
#pragma unroll
            for (int r = 0; r < 4; ++r) { ee[mt][r] = __expf(SCALE * (Sc[mt][nt][r] - m)); s += ee[mt][r]; }
        s += __shfl_xor(s, 16);
        s += __shfl_xor(s, 32);
        float inv = 1.f / s;
        int krow = nt * 16 + l15;
#pragma unroll
        for (int mt = 0; mt < 4; ++mt)
#pragma unroll
            for (int r = 0; r < 4; ++r)
                T[krow][mt * 16 + l4 * 4 + r] = f2bf(ee[mt][r] * inv);
    }

    f32x4 O[4][4];
#pragma unroll
    for (int x = 0; x < 4; ++x)
#pragma unroll
        for (int y = 0; y < 4; ++y) O[x][y] = fz;
#pragma unroll
    for (int ks = 0; ks < 2; ++ks)
#pragma unroll
        for (int mt = 0; mt < 4; ++mt)
#pragma unroll
            for (int nt = 0; nt < 4; ++nt)
                O[mt][nt] = mma(pa[mt][ks], cb[nt][ks], O[mt][nt]);

    float* cO = out;
#pragma unroll
    for (int mt = 0; mt < 4; ++mt)
#pragma unroll
        for (int nt = 0; nt < 4; ++nt)
#pragma unroll
            for (int r = 0; r < 4; ++r) {
                int qrow = mt * 16 + l4 * 4 + r;
                cO[((size_t)b * SEQ + qrow) * (NH * 64) + wv * 64 + nt * 16 + l15] = O[mt][nt][r];
            }

    s16x8 p2a[4][2];
#pragma unroll
    for (int mt = 0; mt < 4; ++mt)
#pragma unroll
        for (int ks = 0; ks < 2; ++ks)
            p2a[mt][ks] = *(const s16x8*)&T[mt * 16 + l15][ks * 32 + l4 * 8];

#pragma unroll
    for (int x = 0; x < 4; ++x)
#pragma unroll
        for (int y = 0; y < 4; ++y) O[x][y] = fz;
#pragma unroll
    for (int ks = 0; ks < 2; ++ks)
#pragma unroll
        for (int mt = 0; mt < 4; ++mt)
#pragma unroll
            for (int nt = 0; nt < 4; ++nt)
                O[mt][nt] = mma(p2a[mt][ks], qb[nt][ks], O[mt][nt]);

    float* qO = out + (size_t)NB * SEQ * NH * 64;
#pragma unroll
    for (int mt = 0; mt < 4; ++mt)
#pragma unroll
        for (int nt = 0; nt < 4; ++nt)
#pragma unroll
            for (int r = 0; r < 4; ++r) {
                int krow = mt * 16 + l4 * 4 + r;
                qO[((size_t)b * SEQ + krow) * (NH * 64) + wv * 64 + nt * 16 + l15] = O[mt][nt][r];
            }
}

extern "C" void kernel_launch(void* const* d_in, const int* in_sizes, int n_in,
                              void* d_out, int out_size, void* d_ws, size_t ws_size,
                              hipStream_t stream) {
    const float* query   = (const float*)d_in[0];
    const float* context = (const float*)d_in[1];
    const float* Wq      = (const float*)d_in[2];
    const float* bq      = (const float*)d_in[3];
    const float* Wc      = (const float*)d_in[4];
    const float* bc      = (const float*)d_in[5];
    float* out = (float*)d_out;

    unsigned short* wfrag = (unsigned short*)d_ws;              // 1 MB
    unsigned short* acts  = wfrag + 524288;                     // 134.2 MB swz bf16 acts
    const size_t need = (524288 + (size_t)2 * NB * 4096 * 8) * sizeof(unsigned short);

    prep_weights<<<256, 256, 0, stream>>>(Wq, Wc, wfrag);
    if (ws_size >= need) {
        prep_acts_swz<<<16384, 256, 0, stream>>>(query, context, acts);
        fused_gll<<<256, 512, 0, stream>>>(acts, bq, bc, wfrag, out);
    } else {
        fused_b<<<NB, 512, 0, stream>>>(query, context, bq, bc, wfrag, out);
    }
}

// Round 17
// 190.342 us; speedup vs baseline: 3.1431x; 3.1431x over previous
//
#include <hip/hip_runtime.h>
#include <hip/hip_bf16.h>

typedef float  f32x4 __attribute__((ext_vector_type(4)));
typedef short  s16x8 __attribute__((ext_vector_type(8)));

#define NB   1024
#define SEQ  64
#define DIM  512
#define NH   8
#define SCALE 0.044194173824159216f

// round-half-up f32->bf16: 2 VALU ops
static __device__ __forceinline__ unsigned short f2bf(float f) {
    unsigned u = __builtin_bit_cast(unsigned, f);
    return (unsigned short)((u + 0x8000u) >> 16);
}

static __device__ __forceinline__ f32x4 mma(s16x8 a, s16x8 b, f32x4 c) {
    return __builtin_amdgcn_mfma_f32_16x16x32_bf16(a, b, c, 0, 0, 0);
}

static __device__ __forceinline__ s16x8 cvt2(float4 a, float4 b) {
    s16x8 x;
    x[0] = (short)f2bf(a.x); x[1] = (short)f2bf(a.y);
    x[2] = (short)f2bf(a.z); x[3] = (short)f2bf(a.w);
    x[4] = (short)f2bf(b.x); x[5] = (short)f2bf(b.y);
    x[6] = (short)f2bf(b.z); x[7] = (short)f2bf(b.w);
    return x;
}

// Pre-kernel: Wq, Wc (f32 [512][512] row-major [k][n]) -> bf16 B-fragment order.
__global__ __launch_bounds__(256) void prep_weights(
    const float* __restrict__ Wq, const float* __restrict__ Wc,
    unsigned short* __restrict__ wf)
{
    int gid  = blockIdx.x * 256 + threadIdx.x;   // 0..65535
    int m    = gid >> 15;
    int tile = (gid >> 10) & 31;
    int ks   = (gid >> 6) & 15;
    int lane = gid & 63;
    const float* W = m ? Wc : Wq;
    int col = tile * 16 + (lane & 15);
    int k0  = ks * 32 + (lane >> 4) * 8;
    unsigned short* dst = wf + (size_t)gid * 8;
#pragma unroll
    for (int j = 0; j < 8; ++j)
        dst[j] = f2bf(W[(size_t)(k0 + j) * DIM + col]);
}

// ====================== Fused kernel: one block = one batch b ======================
// R13 structure with staggered staging (R17):
//   stage C only -> bar -> issue Q-half0 loads (32 VGPR, die before tail)
//   -> GEMM-C (covers Q-half0 latency) -> bar -> write Qh0, issue Q-half1
//   -> Cp->T + cb (covers Qh1) -> write Qh1 -> bar -> GEMM-Q -> tail
//   (no post-GEMM-Q barrier: all cross-wave reads already fenced; tail is
//   own-wave-tile only -> waves desync, store bursts stagger).
// Exposed HBM read per block: C's 128 KB only (R13 exposed 256 KB).
// Proven-verbatim pieces: XOR-swizzled stage layout (R12, conflicts=0),
// GEMM16 algebra, in-register tail (R3/R13), f2bf numerics.
// FAILED-mechanism ledger (do not revisit): min-waves launch_bounds clamps
// (R2/R7 spills), multi-block co-residency with 64-AGPR acc (R6/8/9/11/14),
// reg-held cross-TAIL prefetch (R15 spill), global_load_lds across barriers
// (R16 drain + traffic blowup).
__global__ __launch_bounds__(512) void fused_b(
    const float* __restrict__ query,
    const float* __restrict__ context,
    const float* __restrict__ bq,
    const float* __restrict__ bc,
    const unsigned short* __restrict__ wf,
    float* __restrict__ out)
{
    __shared__ unsigned short smem[69632];   // Q 32768 + region2 36864 shorts
    unsigned short* Q = smem;
    unsigned short* C = smem + 32768;

    const int tid  = threadIdx.x;
    const int lane = tid & 63;
    const int wv   = tid >> 6;          // wave id = head
    const int l15  = lane & 15;
    const int l4   = lane >> 4;
    const int b    = blockIdx.x;

    const float* gq = query   + (size_t)b * SEQ * DIM;
    const float* gc = context + (size_t)b * SEQ * DIM;

    const int row = tid >> 3;
    const int cw  = tid & 7;
    const int wsb = (cw >> 2) * 256 + (cw & 3) * 64 + row;
    const float* qsrc = gq + (size_t)row * DIM + cw * 8;
    const float* csrc = gc + (size_t)row * DIM + cw * 8;

    unsigned short (*T)[72] = (unsigned short(*)[72])(C + wv * 4608);
    const f32x4 fz = {0.f, 0.f, 0.f, 0.f};

    // ---------------- Phase A: stage C tile only ----------------
    {
        float4 lc[16];
#pragma unroll
        for (int p = 0; p < 8; ++p) {
            lc[2 * p]     = *(const float4*)(csrc + p * 64);
            lc[2 * p + 1] = *(const float4*)(csrc + p * 64 + 4);
        }
#pragma unroll
        for (int p = 0; p < 8; ++p)
            *(s16x8*)&C[((p * 512 + wsb) ^ cw) * 8] = cvt2(lc[2 * p], lc[2 * p + 1]);
    }
    __syncthreads();

    // ---------------- Phase B: issue Q-half0 loads (fly under GEMM-C) -----
    float4 lq[8];
#pragma unroll
    for (int p = 0; p < 4; ++p) {
        lq[2 * p]     = *(const float4*)(qsrc + p * 64);
        lq[2 * p + 1] = *(const float4*)(qsrc + p * 64 + 4);
    }

    f32x4 acc[4][4];
#pragma unroll
    for (int x = 0; x < 4; ++x)
#pragma unroll
        for (int y = 0; y < 4; ++y) acc[x][y] = fz;

    // ---------------- GEMM-C ----------------
    {
        const unsigned short* wfm = wf + 262144;
#pragma unroll
        for (int ks = 0; ks < 16; ++ks) {
            const int p  = ks >> 1;
            const int kk = ks & 1;
            s16x8 af[4], bf[4];
#pragma unroll
            for (int mt = 0; mt < 4; ++mt) {
                const int s = p * 512 + kk * 256 + l4 * 64 + mt * 16 + l15;
                af[mt] = *(const s16x8*)&C[(s ^ (4 * kk + l4)) * 8];
            }
#pragma unroll
            for (int nt = 0; nt < 4; ++nt)
                bf[nt] = *(const s16x8*)(wfm +
                         ((size_t)((wv * 4 + nt) * 16 + ks) * 64 + lane) * 8);
#pragma unroll
            for (int mt = 0; mt < 4; ++mt)
#pragma unroll
                for (int nt = 0; nt < 4; ++nt)
                    acc[mt][nt] = mma(af[mt], bf[nt], acc[mt][nt]);
        }
    }
    __syncthreads();   // all reads of C done (T may overwrite); Qh0 arrived

    // write Q-half0 (cols 0..255); issue Q-half1 (flies under Cp->T + cb)
#pragma unroll
    for (int p = 0; p < 4; ++p)
        *(s16x8*)&Q[((p * 512 + wsb) ^ cw) * 8] = cvt2(lq[2 * p], lq[2 * p + 1]);
#pragma unroll
    for (int p = 0; p < 4; ++p) {
        lq[2 * p]     = *(const float4*)(qsrc + 256 + p * 64);
        lq[2 * p + 1] = *(const float4*)(qsrc + 256 + p * 64 + 4);
    }

    // Cp + bias -> per-wave tail tile; cb frags (Cp^T = contig rows)
#pragma unroll
    for (int nt = 0; nt < 4; ++nt) {
        float bcv = bc[wv * 64 + nt * 16 + l15];
#pragma unroll
        for (int mt = 0; mt < 4; ++mt)
#pragma unroll
            for (int r = 0; r < 4; ++r)
                T[mt * 16 + l4 * 4 + r][nt * 16 + l15] = f2bf(acc[mt][nt][r] + bcv);
    }
    s16x8 cb[4][2];
#pragma unroll
    for (int nt = 0; nt < 4; ++nt)
#pragma unroll
        for (int ks = 0; ks < 2; ++ks)
            cb[nt][ks] = *(const s16x8*)&T[nt * 16 + l15][ks * 32 + l4 * 8];

    // write Q-half1 (cols 256..511)
#pragma unroll
    for (int p = 0; p < 4; ++p)
        *(s16x8*)&Q[(((p + 4) * 512 + wsb) ^ cw) * 8] = cvt2(lq[2 * p], lq[2 * p + 1]);
    __syncthreads();   // all waves' Q rows staged before GEMM-Q

    // ---------------- GEMM-Q (same acc regs) ----------------
#pragma unroll
    for (int x = 0; x < 4; ++x)
#pragma unroll
        for (int y = 0; y < 4; ++y) acc[x][y] = fz;
    {
#pragma unroll
        for (int ks = 0; ks < 16; ++ks) {
            const int p  = ks >> 1;
            const int kk = ks & 1;
            s16x8 af[4], bf[4];
#pragma unroll
            for (int mt = 0; mt < 4; ++mt) {
                const int s = p * 512 + kk * 256 + l4 * 64 + mt * 16 + l15;
                af[mt] = *(const s16x8*)&Q[(s ^ (4 * kk + l4)) * 8];
            }
#pragma unroll
            for (int nt = 0; nt < 4; ++nt)
                bf[nt] = *(const s16x8*)(wf +
                         ((size_t)((wv * 4 + nt) * 16 + ks) * 64 + lane) * 8);
#pragma unroll
            for (int mt = 0; mt < 4; ++mt)
#pragma unroll
                for (int nt = 0; nt < 4; ++nt)
                    acc[mt][nt] = mma(af[mt], bf[nt], acc[mt][nt]);
        }
    }
    // no barrier: tail below touches only this wave's own T tile / registers

    // Qp + bias -> T (overwrites Cp; cb in regs); qa/qb frags
#pragma unroll
    for (int nt = 0; nt < 4; ++nt) {
        float bqv = bq[wv * 64 + nt * 16 + l15];
#pragma unroll
        for (int mt = 0; mt < 4; ++mt)
#pragma unroll
            for (int r = 0; r < 4; ++r)
                T[mt * 16 + l4 * 4 + r][nt * 16 + l15] = f2bf(acc[mt][nt][r] + bqv);
    }
    s16x8 qa[4][2], qb[4][2];
#pragma unroll
    for (int mt = 0; mt < 4; ++mt)
#pragma unroll
        for (int ks = 0; ks < 2; ++ks)
            qa[mt][ks] = *(const s16x8*)&T[mt * 16 + l15][ks * 32 + l4 * 8];
#pragma unroll
    for (int nt = 0; nt < 4; ++nt)
#pragma unroll
        for (int ks = 0; ks < 2; ++ks) {
            s16x8 v;
#pragma unroll
            for (int j = 0; j < 8; ++j)
                v[j] = (short)T[ks * 32 + l4 * 8 + j][nt * 16 + l15];
            qb[nt][ks] = v;
        }

    // ---------------- attention tail (R3/R13-proven) ----------------
    f32x4 Sc[4][4];
#pragma unroll
    for (int x = 0; x < 4; ++x)
#pragma unroll
        for (int y = 0; y < 4; ++y) Sc[x][y] = fz;
#pragma unroll
    for (int ks = 0; ks < 2; ++ks)
#pragma unroll
        for (int mt = 0; mt < 4; ++mt)
#pragma unroll
            for (int nt = 0; nt < 4; ++nt)
                Sc[mt][nt] = mma(qa[mt][ks], cb[nt][ks], Sc[mt][nt]);

    // softmax over keys (rows): P1 -> T
#pragma unroll
    for (int mt = 0; mt < 4; ++mt)
#pragma unroll
        for (int r = 0; r < 4; ++r) {
            float m = fmaxf(fmaxf(Sc[mt][0][r], Sc[mt][1][r]),
                            fmaxf(Sc[mt][2][r], Sc[mt][3][r]));
            m = fmaxf(m, __shfl_xor(m, 1));
            m = fmaxf(m, __shfl_xor(m, 2));
            m = fmaxf(m, __shfl_xor(m, 4));
            m = fmaxf(m, __shfl_xor(m, 8));
            float e[4], s = 0.f;
#pragma unroll
            for (int nt = 0; nt < 4; ++nt) { e[nt] = __expf(SCALE * (Sc[mt][nt][r] - m)); s += e[nt]; }
            s += __shfl_xor(s, 1);
            s += __shfl_xor(s, 2);
            s += __shfl_xor(s, 4);
            s += __shfl_xor(s, 8);
            float inv = 1.f / s;
            int r3 = mt * 16 + l4 * 4 + r;
#pragma unroll
            for (int nt = 0; nt < 4; ++nt)
                T[r3][nt * 16 + l15] = f2bf(e[nt] * inv);
        }

    s16x8 pa[4][2];
#pragma unroll
    for (int mt = 0; mt < 4; ++mt)
#pragma unroll
        for (int ks = 0; ks < 2; ++ks)
            pa[mt][ks] = *(const s16x8*)&T[mt * 16 + l15][ks * 32 + l4 * 8];

    // softmax over queries (cols): P2^T -> T
#pragma unroll
    for (int nt = 0; nt < 4; ++nt) {
        float m = -1e30f;
#pragma unroll
        for (int mt = 0; mt < 4; ++mt)
#pragma unroll
            for (int r = 0; r < 4; ++r) m = fmaxf(m, Sc[mt][nt][r]);
        m = fmaxf(m, __shfl_xor(m, 16));
        m = fmaxf(m, __shfl_xor(m, 32));
        float ee[4][4], s = 0.f;
#pragma unroll
        for (int mt = 0; mt < 4; ++mt)
#pragma unroll
            for (int r = 0; r < 4; ++r) { ee[mt][r] = __expf(SCALE * (Sc[mt][nt][r] - m)); s += ee[mt][r]; }
        s += __shfl_xor(s, 16);
        s += __shfl_xor(s, 32);
        float inv = 1.f / s;
        int krow = nt * 16 + l15;
#pragma unroll
        for (int mt = 0; mt < 4; ++mt)
#pragma unroll
            for (int r = 0; r < 4; ++r)
                T[krow][mt * 16 + l4 * 4 + r] = f2bf(ee[mt][r] * inv);
    }

    // c_coattn = P1 @ Cp^T ; store
    f32x4 O[4][4];
#pragma unroll
    for (int x = 0; x < 4; ++x)
#pragma unroll
        for (int y = 0; y < 4; ++y) O[x][y] = fz;
#pragma unroll
    for (int ks = 0; ks < 2; ++ks)
#pragma unroll
        for (int mt = 0; mt < 4; ++mt)
#pragma unroll
            for (int nt = 0; nt < 4; ++nt)
                O[mt][nt] = mma(pa[mt][ks], cb[nt][ks], O[mt][nt]);

    float* cO = out;
#pragma unroll
    for (int mt = 0; mt < 4; ++mt)
#pragma unroll
        for (int nt = 0; nt < 4; ++nt)
#pragma unroll
            for (int r = 0; r < 4; ++r) {
                int qrow = mt * 16 + l4 * 4 + r;
                cO[((size_t)b * SEQ + qrow) * (NH * 64) + wv * 64 + nt * 16 + l15] = O[mt][nt][r];
            }

    // q_coattn = P2^T @ Qp ; store
    s16x8 p2a[4][2];
#pragma unroll
    for (int mt = 0; mt < 4; ++mt)
#pragma unroll
        for (int ks = 0; ks < 2; ++ks)
            p2a[mt][ks] = *(const s16x8*)&T[mt * 16 + l15][ks * 32 + l4 * 8];

#pragma unroll
    for (int x = 0; x < 4; ++x)
#pragma unroll
        for (int y = 0; y < 4; ++y) O[x][y] = fz;
#pragma unroll
    for (int ks = 0; ks < 2; ++ks)
#pragma unroll
        for (int mt = 0; mt < 4; ++mt)
#pragma unroll
            for (int nt = 0; nt < 4; ++nt)
                O[mt][nt] = mma(p2a[mt][ks], qb[nt][ks], O[mt][nt]);

    float* qO = out + (size_t)NB * SEQ * NH * 64;
#pragma unroll
    for (int mt = 0; mt < 4; ++mt)
#pragma unroll
        for (int nt = 0; nt < 4; ++nt)
#pragma unroll
            for (int r = 0; r < 4; ++r) {
                int krow = mt * 16 + l4 * 4 + r;
                qO[((size_t)b * SEQ + krow) * (NH * 64) + wv * 64 + nt * 16 + l15] = O[mt][nt][r];
            }
}

extern "C" void kernel_launch(void* const* d_in, const int* in_sizes, int n_in,
                              void* d_out, int out_size, void* d_ws, size_t ws_size,
                              hipStream_t stream) {
    const float* query   = (const float*)d_in[0];
    const float* context = (const float*)d_in[1];
    const float* Wq      = (const float*)d_in[2];
    const float* bq      = (const float*)d_in[3];
    const float* Wc      = (const float*)d_in[4];
    const float* bc      = (const float*)d_in[5];
    float* out = (float*)d_out;

    unsigned short* wfrag = (unsigned short*)d_ws;   // 1 MB bf16 weight frags

    prep_weights<<<256, 256, 0, stream>>>(Wq, Wc, wfrag);
    fused_b<<<NB, 512, 0, stream>>>(query, context, bq, bc, wfrag, out);
}